// Round 7
// baseline (371.014 us; speedup 1.0000x reference)
//
#include <hip/hip_runtime.h>

// ForgetMult: h_t = f_t*x_t + (1-f_t)*h_{t-1}, shapes (S=4096, B=16, H=512) fp32.
// R10 = R9 resubmitted (R9 bench died to container infra failure, no data).
// Theory: force memory-level parallelism. Evidence: VGPR=36 invariant across
// R5-R8 (scheduler sinks loads into consumers -> ~2-4 in flight/wave) and app
// BW pinned at ~2.5-2.6 TB/s regardless of occupancy/contiguity, while
// LLC-warm fm_apply runs >=3.8 TB/s and simple read kernels hit 4.9 TB/s.
// Fix: per thread, issue ALL 32 tile loads (16 rows x f,x -> 128 VGPRs,
// static-indexed arrays) then __builtin_amdgcn_sched_barrier(0) so the
// scheduler cannot sink them, then the FMA chain. __launch_bounds__(256,2)
// lifts the VGPR cap. Same 3-kernel two-level scan (TT=16), hprev in-place
// in aggB, nontemporal out stores.

#define SQ      4096
#define NC4     2048            // float4 columns = 16*512/4
#define NCH     8192            // scalar chains
#define TT      16              // timesteps per chunk
#define NCHUNK  (SQ / TT)       // 256
#define GRID1   (NCHUNK * 8)    // 2048 blocks for K1/K3

typedef float floatx4 __attribute__((ext_vector_type(4)));

// ---- K1: per-chunk aggregates A = prod(1-f), B = local scan ----
__global__ __launch_bounds__(256, 2)
void fm_agg(const floatx4* __restrict__ f4, const floatx4* __restrict__ x4,
            floatx4* __restrict__ aggA, floatx4* __restrict__ aggB)
{
  const int tid   = threadIdx.x;
  const int chunk = blockIdx.x >> 3;
  const int col   = ((blockIdx.x & 7) << 8) + tid;
  const size_t base = (size_t)(chunk * TT) * NC4 + col;

  // Issue the whole chunk-tile: 32 outstanding loads per thread.
  floatx4 ff[TT], xx[TT];
#pragma unroll
  for (int t = 0; t < TT; ++t) {
    ff[t] = f4[base + (size_t)t * NC4];
    xx[t] = x4[base + (size_t)t * NC4];
  }
  __builtin_amdgcn_sched_barrier(0);   // loads may not sink past this point

  floatx4 A = {1.f, 1.f, 1.f, 1.f};
  floatx4 B = {0.f, 0.f, 0.f, 0.f};
#pragma unroll
  for (int t = 0; t < TT; ++t) {
    B.x = fmaf(ff[t].x, xx[t].x - B.x, B.x);
    B.y = fmaf(ff[t].y, xx[t].y - B.y, B.y);
    B.z = fmaf(ff[t].z, xx[t].z - B.z, B.z);
    B.w = fmaf(ff[t].w, xx[t].w - B.w, B.w);
    A.x = fmaf(-ff[t].x, A.x, A.x);
    A.y = fmaf(-ff[t].y, A.y, A.y);
    A.z = fmaf(-ff[t].z, A.z, A.z);
    A.w = fmaf(-ff[t].w, A.w, A.w);
  }
  aggA[(size_t)chunk * NC4 + col] = A;
  aggB[(size_t)chunk * NC4 + col] = B;
}

// ---- K2: scan chunk aggregates per scalar chain, hprev written IN PLACE ----
// Scalar view of aggA/aggB: [chunk][8192 chains]. For each chunk c: read (a,b),
// store incoming h into the B slot (becomes hprev for K3), advance h = a*h+b.
__global__ __launch_bounds__(256, 4)
void fm_mid(const float* __restrict__ A, float* __restrict__ B,
            const float* __restrict__ h0)
{
  const int chain = blockIdx.x * 256 + threadIdx.x;
  float h = h0[chain];
  for (int cb = 0; cb < NCHUNK / 16; ++cb) {
    float a[16], b[16];
#pragma unroll
    for (int i = 0; i < 16; ++i) {
      const size_t idx = (size_t)(cb * 16 + i) * NCH + chain;
      a[i] = A[idx];
      b[i] = B[idx];
    }
#pragma unroll
    for (int i = 0; i < 16; ++i) {
      const size_t idx = (size_t)(cb * 16 + i) * NCH + chain;
      B[idx] = h;                    // hprev entering chunk cb*16+i
      h = fmaf(a[i], h, b[i]);
    }
  }
}

// ---- K3: apply recurrence from hprev (= aggB), deep-MLP + NT out ----
__global__ __launch_bounds__(256, 2)
void fm_apply(const floatx4* __restrict__ f4, const floatx4* __restrict__ x4,
              const floatx4* __restrict__ hprev4, floatx4* __restrict__ out4)
{
  const int tid   = threadIdx.x;
  const int chunk = (NCHUNK - 1) - (blockIdx.x >> 3);   // descending: LLC reuse
  const int col   = ((blockIdx.x & 7) << 8) + tid;
  const size_t base = (size_t)(chunk * TT) * NC4 + col;

  floatx4 ff[TT], xx[TT];
#pragma unroll
  for (int t = 0; t < TT; ++t) {
    ff[t] = f4[base + (size_t)t * NC4];
    xx[t] = x4[base + (size_t)t * NC4];
  }
  floatx4 h = hprev4[(size_t)chunk * NC4 + col];
  __builtin_amdgcn_sched_barrier(0);   // loads may not sink past this point

#pragma unroll
  for (int t = 0; t < TT; ++t) {
    h.x = fmaf(ff[t].x, xx[t].x - h.x, h.x);
    h.y = fmaf(ff[t].y, xx[t].y - h.y, h.y);
    h.z = fmaf(ff[t].z, xx[t].z - h.z, h.z);
    h.w = fmaf(ff[t].w, xx[t].w - h.w, h.w);
    // Nontemporal: don't let the 128 MB output stream evict f,x from LLC.
    __builtin_nontemporal_store(h, &out4[base + (size_t)t * NC4]);
  }
}

// Fallback (only if ws_size is too small): one float4-column per thread.
__global__ void fm_naive(const float4* __restrict__ f4, const float4* __restrict__ x4,
                         const float4* __restrict__ h04, float4* __restrict__ out4)
{
  const int col = blockIdx.x * blockDim.x + threadIdx.x;
  if (col >= NC4) return;
  float4 h = h04[col];
  for (int t = 0; t < SQ; ++t) {
    const size_t idx = (size_t)t * NC4 + col;
    const float4 ff = f4[idx], xx = x4[idx];
    h.x = fmaf(ff.x, xx.x - h.x, h.x);
    h.y = fmaf(ff.y, xx.y - h.y, h.y);
    h.z = fmaf(ff.z, xx.z - h.z, h.z);
    h.w = fmaf(ff.w, xx.w - h.w, h.w);
    out4[idx] = h;
  }
}

extern "C" void kernel_launch(void* const* d_in, const int* in_sizes, int n_in,
                              void* d_out, int out_size, void* d_ws, size_t ws_size,
                              hipStream_t stream)
{
  const floatx4* f4  = (const floatx4*)d_in[0];
  const floatx4* x4  = (const floatx4*)d_in[1];
  const float*   h0  = (const float*)d_in[2];
  floatx4* out4 = (floatx4*)d_out;

  const size_t AGG = (size_t)NCHUNK * NC4 * 16;   // 8 MB per aggregate array

  if (ws_size >= 2 * AGG) {                        // 16 MB (proven available)
    floatx4* aggA = (floatx4*)d_ws;
    floatx4* aggB = (floatx4*)((char*)d_ws + AGG);
    fm_agg<<<GRID1, 256, 0, stream>>>(f4, x4, aggA, aggB);
    fm_mid<<<NCH / 256, 256, 0, stream>>>((const float*)aggA,
                                          (float*)aggB, h0);
    fm_apply<<<GRID1, 256, 0, stream>>>(f4, x4, (const floatx4*)aggB, out4);
  } else {
    fm_naive<<<(NC4 + 255) / 256, 256, 0, stream>>>((const float4*)f4,
                                                    (const float4*)x4,
                                                    (const float4*)h0,
                                                    (float4*)out4);
  }
}